// Round 1
// 375.310 us; speedup vs baseline: 1.0242x; 1.0242x over previous
//
#include <hip/hip_runtime.h>

typedef __attribute__((ext_vector_type(8))) short short8;
typedef __attribute__((ext_vector_type(8))) unsigned short ushort8;
typedef __attribute__((ext_vector_type(4))) unsigned short us4;
typedef __attribute__((ext_vector_type(4))) float f32x4;
typedef __attribute__((ext_vector_type(4))) int i32x4;

#define S_LEN 2048
#define D_MODEL 1024
#define N_HEADS 16
#define HEAD_DIM 64

__device__ __forceinline__ unsigned short f2bf(float f) {
  union { float f; unsigned u; } x; x.f = f;
  unsigned r = x.u + 0x7FFFu + ((x.u >> 16) & 1u);
  return (unsigned short)(r >> 16);
}

// pack two f32 -> (bf16(a) | bf16(b)<<16), round-half-up, 3 VALU ops
__device__ __forceinline__ int pkbf(float a, float b) {
  union { float f; unsigned u; } x, y;
  x.f = a; y.f = b;
  return (int)__builtin_amdgcn_perm(y.u + 0x8000u, x.u + 0x8000u, 0x07060302u);
}

// ---------- fused fp32 -> bf16 convert for q,k,v ----------
__global__ __launch_bounds__(256) void cvt3_kernel(const float* __restrict__ a,
                                                   const float* __restrict__ b,
                                                   const float* __restrict__ c,
                                                   unsigned short* __restrict__ oa,
                                                   unsigned short* __restrict__ ob,
                                                   unsigned short* __restrict__ oc) {
  int bid = blockIdx.x;
  const float* in = (bid < 4096) ? a : (bid < 8192 ? b : c);
  unsigned short* out = (bid < 4096) ? oa : (bid < 8192 ? ob : oc);
  int i = (bid & 4095) * 256 + threadIdx.x;
  const f32x4* in4 = (const f32x4*)in;
  f32x4 x = in4[2 * i], y = in4[2 * i + 1];
  i32x4 o;
  o[0] = pkbf(x[0], x[1]);
  o[1] = pkbf(x[2], x[3]);
  o[2] = pkbf(y[0], y[1]);
  o[3] = pkbf(y[2], y[3]);
  ((i32x4*)out)[i] = o;
}

// ---------- all 4 weights: W [K][N] fp32 -> Wt [N][K] bf16, one dispatch ----------
__global__ __launch_bounds__(256) void transpose_w4(
    const float* __restrict__ Wq, const float* __restrict__ Wk,
    const float* __restrict__ Wv, const float* __restrict__ Wo,
    unsigned short* __restrict__ wqkvT, unsigned short* __restrict__ woT) {
  __shared__ float tile[64][65];
  const int z = blockIdx.z;
  const float* W = (z == 0) ? Wq : (z == 1) ? Wk : (z == 2) ? Wv : Wo;
  unsigned short* Wt = (z < 3) ? (wqkvT + (size_t)z * D_MODEL * D_MODEL) : woT;
  const int no = blockIdx.x * 64, ko = blockIdx.y * 64;
  const int tx = threadIdx.x & 63, ty = threadIdx.x >> 6;
  for (int r = ty; r < 64; r += 4)
    tile[r][tx] = W[(size_t)(ko + r) * D_MODEL + no + tx];
  __syncthreads();
  for (int r = ty; r < 64; r += 4)
    Wt[(size_t)(no + r) * D_MODEL + ko + tx] = f2bf(tile[tx][r]);
}

// ---------- 128x128x(BK=64) bf16 GEMM ----------
// MODE 0: fused QKV, N=3072; sel=n0>>10 picks A/bias/out.
//   sel 0,1 (Q,K): bf16 head-split [B,H,S,64] via LDS-transposed stores.
//   sel 2   (V):   bf16 TRANSPOSED [B,H,64,S] written directly.
// MODE 1: out proj, N=1024, fp32 row-major out via LDS-transposed dwordx4 stores.
template <int MODE>
__global__ __launch_bounds__(256) void proj_gemm(
    const unsigned short* __restrict__ A0,
    const unsigned short* __restrict__ A1,
    const unsigned short* __restrict__ A2,
    const unsigned short* __restrict__ Bt,
    const float* __restrict__ b0p, const float* __restrict__ b1p,
    const float* __restrict__ b2p,
    void* __restrict__ o0, void* __restrict__ o1, void* __restrict__ o2,
    float qscale) {
  __shared__ __align__(16) unsigned short sm[16384];  // As | Bs, reused by epilogue
  unsigned short* As = sm;
  unsigned short* Bs = sm + 8192;
  const int tid = threadIdx.x;
  const int wave = tid >> 6, lane = tid & 63;
  const int quad = lane >> 4, l16 = lane & 15;
  const int m0 = blockIdx.y * 128, n0 = blockIdx.x * 128;
  const int wm = (wave >> 1) * 64, wn = (wave & 1) * 64;

  const int sel = (MODE == 0) ? (n0 >> 10) : 0;
  const unsigned short* A = (MODE == 0) ? (sel == 0 ? A0 : sel == 1 ? A1 : A2) : A0;
  const float* bias = (MODE == 0) ? (sel == 0 ? b0p : sel == 1 ? b1p : b2p) : b0p;
  const float scale = (MODE == 0 && sel == 0) ? qscale : 1.0f;
  const int nb = (MODE == 0) ? (n0 & 1023) : n0;

  f32x4 acc[4][4] = {};

  int grow[4], gcol[4];
  for (int i = 0; i < 4; ++i) {
    int cid = (wave * 4 + i) * 64 + lane;
    int r = cid >> 3;
    grow[i] = r;
    gcol[i] = ((cid & 7) ^ (r & 7)) * 8;
  }

  for (int k0 = 0; k0 < D_MODEL; k0 += 64) {
#pragma unroll
    for (int i = 0; i < 4; ++i) {
      const unsigned short* g = A + (size_t)(m0 + grow[i]) * D_MODEL + k0 + gcol[i];
      __builtin_amdgcn_global_load_lds((const __attribute__((address_space(1))) void*)g,
          (__attribute__((address_space(3))) void*)(As + (wave * 4 + i) * 512), 16, 0, 0);
    }
#pragma unroll
    for (int i = 0; i < 4; ++i) {
      const unsigned short* g = Bt + (size_t)(n0 + grow[i]) * D_MODEL + k0 + gcol[i];
      __builtin_amdgcn_global_load_lds((const __attribute__((address_space(1))) void*)g,
          (__attribute__((address_space(3))) void*)(Bs + (wave * 4 + i) * 512), 16, 0, 0);
    }
    __syncthreads();
#pragma unroll
    for (int t = 0; t < 2; ++t) {
      short8 af[4], bf[4];
#pragma unroll
      for (int i = 0; i < 4; ++i) {
        int r = wm + i * 16 + l16;
        af[i] = *(const short8*)(As + r * 64 + (((t * 4 + quad) ^ (r & 7)) << 3));
      }
#pragma unroll
      for (int j = 0; j < 4; ++j) {
        int r = wn + j * 16 + l16;
        bf[j] = *(const short8*)(Bs + r * 64 + (((t * 4 + quad) ^ (r & 7)) << 3));
      }
#pragma unroll
      for (int i = 0; i < 4; ++i)
#pragma unroll
        for (int j = 0; j < 4; ++j)
          acc[i][j] = __builtin_amdgcn_mfma_f32_16x16x32_bf16(af[i], bf[j], acc[i][j], 0, 0, 0);
    }
    __syncthreads();
  }

  float bv4[4];
#pragma unroll
  for (int j = 0; j < 4; ++j) bv4[j] = bias[nb + wn + j * 16 + l16];

  if (MODE == 0) {
    if (sel < 2) {
      unsigned short* T = As + wave * 1152;
      unsigned short* out = (unsigned short*)(sel == 0 ? o0 : o1);
      const int h = (nb + wn) >> 6;
#pragma unroll
      for (int i = 0; i < 4; ++i) {
#pragma unroll
        for (int j = 0; j < 4; ++j)
#pragma unroll
          for (int r = 0; r < 4; ++r)
            T[(quad * 4 + r) * 72 + j * 16 + l16] = f2bf((acc[i][j][r] + bv4[j]) * scale);
        int m = m0 + wm + i * 16 + l16;
        int b = m >> 11, s = m & 2047;
#pragma unroll
        for (int t = 0; t < 2; ++t) {
          short8 row = *(const short8*)(T + l16 * 72 + t * 32 + quad * 8);
          *(short8*)(out + (((size_t)(b * N_HEADS + h) * S_LEN + s) << 6) + t * 32 + quad * 8) = row;
        }
      }
    } else {
      unsigned short* vt = (unsigned short*)o2;
#pragma unroll
      for (int i = 0; i < 4; ++i) {
        int m = m0 + wm + i * 16 + quad * 4;
        int b = m >> 11, s = m & 2047;
#pragma unroll
        for (int j = 0; j < 4; ++j) {
          int n = nb + wn + j * 16 + l16;
          int h = n >> 6, d = n & 63;
          us4 pv;
#pragma unroll
          for (int r = 0; r < 4; ++r) pv[r] = f2bf(acc[i][j][r] + bv4[j]);
          *(us4*)(vt + (((size_t)(b * N_HEADS + h) * 64 + d) << 11) + s) = pv;
        }
      }
    }
  } else {
    float* Tf = (float*)sm + wave * 1088;
    float* out = (float*)o0;
#pragma unroll
    for (int i = 0; i < 4; ++i) {
#pragma unroll
      for (int j = 0; j < 4; ++j)
#pragma unroll
        for (int r = 0; r < 4; ++r)
          Tf[(quad * 4 + r) * 68 + j * 16 + l16] = acc[i][j][r] + bv4[j];
      int m = m0 + wm + i * 16 + l16;
#pragma unroll
      for (int t = 0; t < 4; ++t) {
        f32x4 row = *(const f32x4*)(Tf + l16 * 68 + t * 16 + quad * 4);
        *(f32x4*)(out + (size_t)m * D_MODEL + nb + wn + t * 16 + quad * 4) = row;
      }
    }
  }
}

// ---------- causal flash attention: R3 q-split structure + 128-q blocks + K/V dbuf ----------
// Q pre-scaled by 0.125*log2(e). Block owns 128 queries (qi*128..); wave owns 32
// (2 strips of 16). K/V staged per 64-key tile, double-buffered; stage(kt+1) is
// issued AFTER the top-of-loop barrier so the barrier's vmcnt(0) drain only waits
// on loads issued a full compute-phase earlier. K/V frag reads shared across strips.
// P^T B-frag transform done with v_permlane{32,16}_swap (VALU pipe) instead of
// ds_bpermute shuffles: removes 32 LDS-pipe ops per tile per wave.
__global__ __launch_bounds__(256, 4) void flash_attn(
    const unsigned short* __restrict__ Qh,  // [B,H,S,64] bf16 (scaled)
    const unsigned short* __restrict__ Kh,  // [B,H,S,64] bf16
    const unsigned short* __restrict__ Vt,  // [B,H,64,S] bf16
    unsigned short* __restrict__ ctx) {     // [B,S,1024] bf16
  __shared__ __align__(16) unsigned short smem[16384];  // 32 KB: 2 x (K 8KB | V 8KB)
  const int tid = threadIdx.x;
  const int wave = tid >> 6, lane = tid & 63;
  const int quad = lane >> 4, l16 = lane & 15;
  const int l7 = l16 & 7;
  const int bh = blockIdx.y;
  // balance: t16 steps by 1 per +256 blocks; fold -> {0,15,1,14,..} so the 4
  // co-resident blocks per CU sum to ~constant causal work
  const int t16 = (blockIdx.x + blockIdx.y + (blockIdx.y >> 4)) & 15;
  const int qi = (t16 & 1) ? (15 - (t16 >> 1)) : (t16 >> 1);
  const int q0 = qi * 128;
  const int nk = 2 * qi + 2;
  const size_t hb = (size_t)bh * (S_LEN * HEAD_DIM);
  const int srow = lane >> 3;
  const int schunk = ((lane & 7) ^ srow) * 8;

  auto stage = [&](int kt, int buf) {
    unsigned short* Kb = smem + buf * 8192;
    unsigned short* Vb = smem + buf * 8192 + 4096;
#pragma unroll
    for (int c = 0; c < 2; ++c) {
      int row = wave * 16 + c * 8 + srow;
      const unsigned short* gk = Kh + hb + (size_t)(kt * 64 + row) * 64 + schunk;
      __builtin_amdgcn_global_load_lds((const __attribute__((address_space(1))) void*)gk,
          (__attribute__((address_space(3))) void*)(Kb + (wave * 16 + c * 8) * 64), 16, 0, 0);
      const unsigned short* gv = Vt + hb + (size_t)row * S_LEN + kt * 64 + schunk;
      __builtin_amdgcn_global_load_lds((const __attribute__((address_space(1))) void*)gv,
          (__attribute__((address_space(3))) void*)(Vb + (wave * 16 + c * 8) * 64), 16, 0, 0);
    }
  };

  stage(0, 0);

  // Q B-fragments for both strips, register-resident (coalesced global reads)
  short8 qf[2][2];
#pragma unroll
  for (int s = 0; s < 2; ++s)
#pragma unroll
    for (int t = 0; t < 2; ++t)
      qf[s][t] = *(const short8*)(Qh + hb +
          (size_t)(q0 + wave * 32 + s * 16 + l16) * 64 + t * 32 + quad * 8);

  f32x4 o[4][2] = {};  // o[ntd][s]: d=ntd*16+quad*4+r, query=strip s col l16
  float rsum[2] = {0.f, 0.f};

  for (int kt = 0; kt < nk; ++kt) {
    __syncthreads();  // drains stage issued last iteration; buf[kt&1] now ready
    if (kt + 1 < nk) stage(kt + 1, (kt + 1) & 1);
    const unsigned short* Kb = smem + (kt & 1) * 8192;
    const unsigned short* Vb = Kb + 4096;

    // wave-uniform skip: all keys of this tile beyond wave's max query
    if (kt * 64 > q0 + wave * 32 + 31) continue;

    // S^T = K Q^T per strip (K A-frags shared across strips)
    f32x4 sc[2][4];
    __builtin_amdgcn_s_setprio(1);
#pragma unroll
    for (int nt = 0; nt < 4; ++nt) {
      short8 k0 = *(const short8*)(Kb + (nt * 16 + l16) * 64 + ((quad ^ l7) << 3));
      short8 k1 = *(const short8*)(Kb + (nt * 16 + l16) * 64 + (((4 + quad) ^ l7) << 3));
#pragma unroll
      for (int s = 0; s < 2; ++s) {
        f32x4 z = {};
        z = __builtin_amdgcn_mfma_f32_16x16x32_bf16(k0, qf[s][0], z, 0, 0, 0);
        sc[s][nt] = __builtin_amdgcn_mfma_f32_16x16x32_bf16(k1, qf[s][1], z, 0, 0, 0);
      }
    }
    __builtin_amdgcn_s_setprio(0);
    if (kt >= 2 * qi) {  // only the last two tiles can touch the diagonal
#pragma unroll
      for (int s = 0; s < 2; ++s) {
        int qg = q0 + wave * 32 + s * 16 + l16;
#pragma unroll
        for (int nt = 0; nt < 4; ++nt) {
          int kg = kt * 64 + nt * 16 + quad * 4;
#pragma unroll
          for (int r = 0; r < 4; ++r)
            if (kg + r > qg) sc[s][nt][r] = -1e30f;
        }
      }
    }

    // fixed-base softmax numerator + P^T B-frag transform.
    // Layout move needed: lane (quad,l16) holds scores for query l16, keys
    // nt*16+quad*4+{0..3}; B-frag wants keys quad*8+{0..7} for query l16 --
    // a pure 4x4 quad redistribution within each l16 column. Done in-register:
    //   permlane32_swap(A,C): A'=[a@q0,a@q1,c@q0,c@q1] C'=[a@q2,a@q3,c@q2,c@q3]
    //   permlane16_swap(A',C''): A''=[a@q0,a@q2,c@q0,c@q2]=i[0]
    //                            C''=[a@q1,a@q3,c@q1,c@q3]=i[2]
    // (matches the R3-verified shfl targets; VALU pipe, no ds_bpermute)
    union { int i[4]; short8 v; } pf[2][2];
#pragma unroll
    for (int s = 0; s < 2; ++s) {
      int pk[4][2];
#pragma unroll
      for (int nt = 0; nt < 4; ++nt) {
        float p0 = exp2f(sc[s][nt][0]);
        float p1 = exp2f(sc[s][nt][1]);
        float p2 = exp2f(sc[s][nt][2]);
        float p3 = exp2f(sc[s][nt][3]);
        rsum[s] += (p0 + p1) + (p2 + p3);
        pk[nt][0] = pkbf(p0, p1);
        pk[nt][1] = pkbf(p2, p3);
      }
#pragma unroll
      for (int t = 0; t < 2; ++t) {
        int A = pk[t * 2][0], C = pk[t * 2 + 1][0];
        int B2 = pk[t * 2][1], D = pk[t * 2 + 1][1];
        asm("v_permlane32_swap_b32 %0, %1" : "+v"(A), "+v"(C));
        asm("v_permlane16_swap_b32 %0, %1" : "+v"(A), "+v"(C));
        asm("v_permlane32_swap_b32 %0, %1" : "+v"(B2), "+v"(D));
        asm("v_permlane16_swap_b32 %0, %1" : "+v"(B2), "+v"(D));
        pf[s][t].i[0] = A;
        pf[s][t].i[1] = B2;
        pf[s][t].i[2] = C;
        pf[s][t].i[3] = D;
      }
    }

    // O^T += V^T P^T (V A-frags shared across strips)
    __builtin_amdgcn_s_setprio(1);
#pragma unroll
    for (int ntd = 0; ntd < 4; ++ntd) {
      short8 v0 = *(const short8*)(Vb + (ntd * 16 + l16) * 64 + ((quad ^ l7) << 3));
      short8 v1 = *(const short8*)(Vb + (ntd * 16 + l16) * 64 + (((4 + quad) ^ l7) << 3));
#pragma unroll
      for (int s = 0; s < 2; ++s) {
        o[ntd][s] = __builtin_amdgcn_mfma_f32_16x16x32_bf16(v0, pf[s][0].v, o[ntd][s], 0, 0, 0);
        o[ntd][s] = __builtin_amdgcn_mfma_f32_16x16x32_bf16(v1, pf[s][1].v, o[ntd][s], 0, 0, 0);
      }
    }
    __builtin_amdgcn_s_setprio(0);
  }

  // l reduction over quads (linear softmax base -> once at the end)
#pragma unroll
  for (int s = 0; s < 2; ++s) {
    rsum[s] += __shfl_xor(rsum[s], 16, 64);
    rsum[s] += __shfl_xor(rsum[s], 32, 64);
  }

  // epilogue: O^T -> LDS transpose -> coalesced stores
  __syncthreads();
  unsigned short* Os = smem;  // [128 q][72]
#pragma unroll
  for (int s = 0; s < 2; ++s) {
    float invl = 1.0f / rsum[s];
#pragma unroll
    for (int ntd = 0; ntd < 4; ++ntd) {
      us4 pk4;
#pragma unroll
      for (int r = 0; r < 4; ++r) pk4[r] = f2bf(o[ntd][s][r] * invl);
      *(us4*)(Os + (wave * 32 + s * 16 + l16) * 72 + ntd * 16 + quad * 4) = pk4;
    }
  }
  __syncthreads();
  const int b = bh >> 4, h = bh & 15;
#pragma unroll
  for (int it = 0; it < 4; ++it) {
    int e = it * 256 + tid;
    int row = e >> 3, c = (e & 7) * 8;
    short8 vrow = *(const short8*)(Os + row * 72 + c);
    *(short8*)(ctx + (size_t)(b * S_LEN + q0 + row) * D_MODEL + h * HEAD_DIM + c) = vrow;
  }
}

// ---------- launch ----------
extern "C" void kernel_launch(void* const* d_in, const int* in_sizes, int n_in,
                              void* d_out, int out_size, void* d_ws, size_t ws_size,
                              hipStream_t stream) {
  (void)in_sizes; (void)n_in; (void)out_size;
  const float* q  = (const float*)d_in[0];
  const float* k  = (const float*)d_in[1];
  const float* v  = (const float*)d_in[2];
  const float* Wq = (const float*)d_in[4];
  const float* bq = (const float*)d_in[5];
  const float* Wk = (const float*)d_in[6];
  const float* bk = (const float*)d_in[7];
  const float* Wv = (const float*)d_in[8];
  const float* bv = (const float*)d_in[9];
  const float* Wo = (const float*)d_in[10];
  const float* bo = (const float*)d_in[11];
  float* out = (float*)d_out;

  if (ws_size < 109051904u) return;
  char* ws = (char*)d_ws;
  unsigned short* xq    = (unsigned short*)(ws);
  unsigned short* xk    = (unsigned short*)(ws + 16777216);
  unsigned short* xv    = (unsigned short*)(ws + 33554432);
  unsigned short* wqkvT = (unsigned short*)(ws + 50331648);  // [3072][1024] = 6 MB
  unsigned short* woT   = (unsigned short*)(ws + 56623104);
  unsigned short* qh    = (unsigned short*)(ws + 58720256);
  unsigned short* kh    = qh + 8388608;
  unsigned short* vt    = kh + 8388608;  // [B,H,64,S] written directly by proj<0>
  unsigned short* ctx   = xq;            // xq dead after QKV projection

  cvt3_kernel<<<12288, 256, 0, stream>>>(q, k, v, xq, xk, xv);
  transpose_w4<<<dim3(16, 16, 4), 256, 0, stream>>>(Wq, Wk, Wv, Wo, wqkvT, woT);
  // fused QKV projection; Q scale folds 1/sqrt(64) and log2(e)
  proj_gemm<0><<<dim3(24, 64), 256, 0, stream>>>(xq, xk, xv, wqkvT, bq, bk, bv,
                                                 qh, kh, vt, 0.125f * 1.44269504088896f);
  flash_attn<<<dim3(16, 64), 256, 0, stream>>>(qh, kh, vt, ctx);
  proj_gemm<1><<<dim3(8, 64), 256, 0, stream>>>(ctx, ctx, ctx, woT, bo, bo, bo,
                                                out, out, out, 1.0f);
}

// Round 2
// 328.905 us; speedup vs baseline: 1.1687x; 1.1411x over previous
//
#include <hip/hip_runtime.h>

typedef __attribute__((ext_vector_type(8))) short short8;
typedef __attribute__((ext_vector_type(8))) unsigned short ushort8;
typedef __attribute__((ext_vector_type(4))) unsigned short us4;
typedef __attribute__((ext_vector_type(4))) float f32x4;
typedef __attribute__((ext_vector_type(4))) int i32x4;

#define S_LEN 2048
#define D_MODEL 1024
#define N_HEADS 16
#define HEAD_DIM 64

__device__ __forceinline__ unsigned short f2bf(float f) {
  union { float f; unsigned u; } x; x.f = f;
  unsigned r = x.u + 0x7FFFu + ((x.u >> 16) & 1u);
  return (unsigned short)(r >> 16);
}

// pack two f32 -> (bf16(a) | bf16(b)<<16), round-half-up, 3 VALU ops
__device__ __forceinline__ int pkbf(float a, float b) {
  union { float f; unsigned u; } x, y;
  x.f = a; y.f = b;
  return (int)__builtin_amdgcn_perm(y.u + 0x8000u, x.u + 0x8000u, 0x07060302u);
}

// ---------- fused fp32 -> bf16 convert for q,k,v ----------
__global__ __launch_bounds__(256) void cvt3_kernel(const float* __restrict__ a,
                                                   const float* __restrict__ b,
                                                   const float* __restrict__ c,
                                                   unsigned short* __restrict__ oa,
                                                   unsigned short* __restrict__ ob,
                                                   unsigned short* __restrict__ oc) {
  int bid = blockIdx.x;
  const float* in = (bid < 4096) ? a : (bid < 8192 ? b : c);
  unsigned short* out = (bid < 4096) ? oa : (bid < 8192 ? ob : oc);
  int i = (bid & 4095) * 256 + threadIdx.x;
  const f32x4* in4 = (const f32x4*)in;
  f32x4 x = in4[2 * i], y = in4[2 * i + 1];
  i32x4 o;
  o[0] = pkbf(x[0], x[1]);
  o[1] = pkbf(x[2], x[3]);
  o[2] = pkbf(y[0], y[1]);
  o[3] = pkbf(y[2], y[3]);
  ((i32x4*)out)[i] = o;
}

// ---------- all 4 weights: W [K][N] fp32 -> Wt [N][K] bf16, one dispatch ----------
__global__ __launch_bounds__(256) void transpose_w4(
    const float* __restrict__ Wq, const float* __restrict__ Wk,
    const float* __restrict__ Wv, const float* __restrict__ Wo,
    unsigned short* __restrict__ wqkvT, unsigned short* __restrict__ woT) {
  __shared__ float tile[64][65];
  const int z = blockIdx.z;
  const float* W = (z == 0) ? Wq : (z == 1) ? Wk : (z == 2) ? Wv : Wo;
  unsigned short* Wt = (z < 3) ? (wqkvT + (size_t)z * D_MODEL * D_MODEL) : woT;
  const int no = blockIdx.x * 64, ko = blockIdx.y * 64;
  const int tx = threadIdx.x & 63, ty = threadIdx.x >> 6;
  for (int r = ty; r < 64; r += 4)
    tile[r][tx] = W[(size_t)(ko + r) * D_MODEL + no + tx];
  __syncthreads();
  for (int r = ty; r < 64; r += 4)
    Wt[(size_t)(no + r) * D_MODEL + ko + tx] = f2bf(tile[tx][r]);
}

// ---------- 128x128x(BK=64) bf16 GEMM ----------
// MODE 0: fused QKV, N=3072; sel=n0>>10 picks A/bias/out.
//   sel 0,1 (Q,K): bf16 head-split [B,H,S,64] via LDS-transposed stores.
//   sel 2   (V):   bf16 TRANSPOSED [B,H,64,S] written directly.
// MODE 1: out proj, N=1024, fp32 row-major out via LDS-transposed dwordx4 stores.
// T1 XCD remap (HW round-robins linear block id across 8 XCDs): each XCD owns a
// contiguous 8-row m-stripe, iterated bx-fastest within one sel, so its L2 holds
// {current A panel window (~1.5MB) + B-sel (2MB)} instead of everything.
template <int MODE>
__global__ __launch_bounds__(256) void proj_gemm(
    const unsigned short* __restrict__ A0,
    const unsigned short* __restrict__ A1,
    const unsigned short* __restrict__ A2,
    const unsigned short* __restrict__ Bt,
    const float* __restrict__ b0p, const float* __restrict__ b1p,
    const float* __restrict__ b2p,
    void* __restrict__ o0, void* __restrict__ o1, void* __restrict__ o2,
    float qscale) {
  __shared__ __align__(16) unsigned short sm[16384];  // As | Bs, reused by epilogue
  unsigned short* As = sm;
  unsigned short* Bs = sm + 8192;
  const int tid = threadIdx.x;
  const int wave = tid >> 6, lane = tid & 63;
  const int quad = lane >> 4, l16 = lane & 15;

  // bijective XCD-locality remap
  const int nlin = blockIdx.y * (MODE == 0 ? 24 : 8) + blockIdx.x;
  const int xcd = nlin & 7;
  const int j = nlin >> 3;  // MODE0: 0..191, MODE1: 0..63
  int bx_eff, by_eff;
  if (MODE == 0) {
    by_eff = xcd * 8 + ((j & 63) >> 3);
    bx_eff = (j >> 6) * 8 + (j & 7);
  } else {
    by_eff = xcd * 8 + (j >> 3);
    bx_eff = j & 7;
  }
  const int m0 = by_eff * 128, n0 = bx_eff * 128;
  const int wm = (wave >> 1) * 64, wn = (wave & 1) * 64;

  const int sel = (MODE == 0) ? (n0 >> 10) : 0;
  const unsigned short* A = (MODE == 0) ? (sel == 0 ? A0 : sel == 1 ? A1 : A2) : A0;
  const float* bias = (MODE == 0) ? (sel == 0 ? b0p : sel == 1 ? b1p : b2p) : b0p;
  const float scale = (MODE == 0 && sel == 0) ? qscale : 1.0f;
  const int nb = (MODE == 0) ? (n0 & 1023) : n0;

  f32x4 acc[4][4] = {};

  int grow[4], gcol[4];
  for (int i = 0; i < 4; ++i) {
    int cid = (wave * 4 + i) * 64 + lane;
    int r = cid >> 3;
    grow[i] = r;
    gcol[i] = ((cid & 7) ^ (r & 7)) * 8;
  }

  for (int k0 = 0; k0 < D_MODEL; k0 += 64) {
#pragma unroll
    for (int i = 0; i < 4; ++i) {
      const unsigned short* g = A + (size_t)(m0 + grow[i]) * D_MODEL + k0 + gcol[i];
      __builtin_amdgcn_global_load_lds((const __attribute__((address_space(1))) void*)g,
          (__attribute__((address_space(3))) void*)(As + (wave * 4 + i) * 512), 16, 0, 0);
    }
#pragma unroll
    for (int i = 0; i < 4; ++i) {
      const unsigned short* g = Bt + (size_t)(n0 + grow[i]) * D_MODEL + k0 + gcol[i];
      __builtin_amdgcn_global_load_lds((const __attribute__((address_space(1))) void*)g,
          (__attribute__((address_space(3))) void*)(Bs + (wave * 4 + i) * 512), 16, 0, 0);
    }
    __syncthreads();
#pragma unroll
    for (int t = 0; t < 2; ++t) {
      short8 af[4], bf[4];
#pragma unroll
      for (int i = 0; i < 4; ++i) {
        int r = wm + i * 16 + l16;
        af[i] = *(const short8*)(As + r * 64 + (((t * 4 + quad) ^ (r & 7)) << 3));
      }
#pragma unroll
      for (int j2 = 0; j2 < 4; ++j2) {
        int r = wn + j2 * 16 + l16;
        bf[j2] = *(const short8*)(Bs + r * 64 + (((t * 4 + quad) ^ (r & 7)) << 3));
      }
#pragma unroll
      for (int i = 0; i < 4; ++i)
#pragma unroll
        for (int j2 = 0; j2 < 4; ++j2)
          acc[i][j2] = __builtin_amdgcn_mfma_f32_16x16x32_bf16(af[i], bf[j2], acc[i][j2], 0, 0, 0);
    }
    __syncthreads();
  }

  float bv4[4];
#pragma unroll
  for (int j2 = 0; j2 < 4; ++j2) bv4[j2] = bias[nb + wn + j2 * 16 + l16];

  if (MODE == 0) {
    if (sel < 2) {
      unsigned short* T = As + wave * 1152;
      unsigned short* out = (unsigned short*)(sel == 0 ? o0 : o1);
      const int h = (nb + wn) >> 6;
#pragma unroll
      for (int i = 0; i < 4; ++i) {
#pragma unroll
        for (int j2 = 0; j2 < 4; ++j2)
#pragma unroll
          for (int r = 0; r < 4; ++r)
            T[(quad * 4 + r) * 72 + j2 * 16 + l16] = f2bf((acc[i][j2][r] + bv4[j2]) * scale);
        int m = m0 + wm + i * 16 + l16;
        int b = m >> 11, s = m & 2047;
#pragma unroll
        for (int t = 0; t < 2; ++t) {
          short8 row = *(const short8*)(T + l16 * 72 + t * 32 + quad * 8);
          *(short8*)(out + (((size_t)(b * N_HEADS + h) * S_LEN + s) << 6) + t * 32 + quad * 8) = row;
        }
      }
    } else {
      unsigned short* vt = (unsigned short*)o2;
#pragma unroll
      for (int i = 0; i < 4; ++i) {
        int m = m0 + wm + i * 16 + quad * 4;
        int b = m >> 11, s = m & 2047;
#pragma unroll
        for (int j2 = 0; j2 < 4; ++j2) {
          int n = nb + wn + j2 * 16 + l16;
          int h = n >> 6, d = n & 63;
          us4 pv;
#pragma unroll
          for (int r = 0; r < 4; ++r) pv[r] = f2bf(acc[i][j2][r] + bv4[j2]);
          *(us4*)(vt + (((size_t)(b * N_HEADS + h) * 64 + d) << 11) + s) = pv;
        }
      }
    }
  } else {
    float* Tf = (float*)sm + wave * 1088;
    float* out = (float*)o0;
#pragma unroll
    for (int i = 0; i < 4; ++i) {
#pragma unroll
      for (int j2 = 0; j2 < 4; ++j2)
#pragma unroll
        for (int r = 0; r < 4; ++r)
          Tf[(quad * 4 + r) * 68 + j2 * 16 + l16] = acc[i][j2][r] + bv4[j2];
      int m = m0 + wm + i * 16 + l16;
#pragma unroll
      for (int t = 0; t < 4; ++t) {
        f32x4 row = *(const f32x4*)(Tf + l16 * 68 + t * 16 + quad * 4);
        *(f32x4*)(out + (size_t)m * D_MODEL + nb + wn + t * 16 + quad * 4) = row;
      }
    }
  }
}

// ---------- causal flash attention: R3 q-split structure + 128-q blocks + K/V dbuf ----------
// Q pre-scaled by 0.125*log2(e). Block owns 128 queries (qi*128..); wave owns 32
// (2 strips of 16). K/V staged per 64-key tile, double-buffered; stage(kt+1) is
// issued AFTER the top-of-loop barrier so the barrier's vmcnt(0) drain only waits
// on loads issued a full compute-phase earlier. K/V frag reads shared across strips.
// P^T B-frag transform via v_permlane{32,16}_swap (VALU pipe, no LDS traffic).
// T1 remap: 8 heads pinned per XCD; the 4 co-resident blocks on a CU are the SAME
// head (shared K/V stream -> L2/L1 hits on the stage loads) with qi values
// {a, 15-a, a+4, 11-a} summing to a constant 30 for causal load balance.
__global__ __launch_bounds__(256, 4) void flash_attn(
    const unsigned short* __restrict__ Qh,  // [B,H,S,64] bf16 (scaled)
    const unsigned short* __restrict__ Kh,  // [B,H,S,64] bf16
    const unsigned short* __restrict__ Vt,  // [B,H,64,S] bf16
    unsigned short* __restrict__ ctx) {     // [B,S,1024] bf16
  __shared__ __align__(16) unsigned short smem[16384];  // 32 KB: 2 x (K 8KB | V 8KB)
  const int tid = threadIdx.x;
  const int wave = tid >> 6, lane = tid & 63;
  const int quad = lane >> 4, l16 = lane & 15;
  const int l7 = l16 & 7;

  // bijective head/XCD remap: n = (qslot<<6) | (hg<<3) | xcd, bh = xcd*8+hg
  const int nlin = blockIdx.y * 16 + blockIdx.x;
  const int xcd = nlin & 7;
  const int rr = nlin >> 3;            // 0..127
  const int bh = xcd * 8 + (rr & 7);   // 8 heads per XCD
  const int qslot = rr >> 3;           // 0..15
  const int qa = qslot & 3, qb = qslot >> 2;
  const int qbase = qa + ((qb >> 1) << 2);
  const int qi = (qb & 1) ? (15 - qbase) : qbase;
  const int q0 = qi * 128;
  const int nk = 2 * qi + 2;
  const size_t hb = (size_t)bh * (S_LEN * HEAD_DIM);
  const int srow = lane >> 3;
  const int schunk = ((lane & 7) ^ srow) * 8;

  auto stage = [&](int kt, int buf) {
    unsigned short* Kb = smem + buf * 8192;
    unsigned short* Vb = smem + buf * 8192 + 4096;
#pragma unroll
    for (int c = 0; c < 2; ++c) {
      int row = wave * 16 + c * 8 + srow;
      const unsigned short* gk = Kh + hb + (size_t)(kt * 64 + row) * 64 + schunk;
      __builtin_amdgcn_global_load_lds((const __attribute__((address_space(1))) void*)gk,
          (__attribute__((address_space(3))) void*)(Kb + (wave * 16 + c * 8) * 64), 16, 0, 0);
      const unsigned short* gv = Vt + hb + (size_t)row * S_LEN + kt * 64 + schunk;
      __builtin_amdgcn_global_load_lds((const __attribute__((address_space(1))) void*)gv,
          (__attribute__((address_space(3))) void*)(Vb + (wave * 16 + c * 8) * 64), 16, 0, 0);
    }
  };

  stage(0, 0);

  // Q B-fragments for both strips, register-resident (coalesced global reads)
  short8 qf[2][2];
#pragma unroll
  for (int s = 0; s < 2; ++s)
#pragma unroll
    for (int t = 0; t < 2; ++t)
      qf[s][t] = *(const short8*)(Qh + hb +
          (size_t)(q0 + wave * 32 + s * 16 + l16) * 64 + t * 32 + quad * 8);

  f32x4 o[4][2] = {};  // o[ntd][s]: d=ntd*16+quad*4+r, query=strip s col l16
  float rsum[2] = {0.f, 0.f};

  for (int kt = 0; kt < nk; ++kt) {
    __syncthreads();  // drains stage issued last iteration; buf[kt&1] now ready
    if (kt + 1 < nk) stage(kt + 1, (kt + 1) & 1);
    const unsigned short* Kb = smem + (kt & 1) * 8192;
    const unsigned short* Vb = Kb + 4096;

    // wave-uniform skip: all keys of this tile beyond wave's max query
    if (kt * 64 > q0 + wave * 32 + 31) continue;

    // S^T = K Q^T per strip (K A-frags shared across strips)
    f32x4 sc[2][4];
    __builtin_amdgcn_s_setprio(1);
#pragma unroll
    for (int nt = 0; nt < 4; ++nt) {
      short8 k0 = *(const short8*)(Kb + (nt * 16 + l16) * 64 + ((quad ^ l7) << 3));
      short8 k1 = *(const short8*)(Kb + (nt * 16 + l16) * 64 + (((4 + quad) ^ l7) << 3));
#pragma unroll
      for (int s = 0; s < 2; ++s) {
        f32x4 z = {};
        z = __builtin_amdgcn_mfma_f32_16x16x32_bf16(k0, qf[s][0], z, 0, 0, 0);
        sc[s][nt] = __builtin_amdgcn_mfma_f32_16x16x32_bf16(k1, qf[s][1], z, 0, 0, 0);
      }
    }
    __builtin_amdgcn_s_setprio(0);
    if (kt >= 2 * qi) {  // only the last two tiles can touch the diagonal
#pragma unroll
      for (int s = 0; s < 2; ++s) {
        int qg = q0 + wave * 32 + s * 16 + l16;
#pragma unroll
        for (int nt = 0; nt < 4; ++nt) {
          int kg = kt * 64 + nt * 16 + quad * 4;
#pragma unroll
          for (int r = 0; r < 4; ++r)
            if (kg + r > qg) sc[s][nt][r] = -1e30f;
        }
      }
    }

    // fixed-base softmax numerator + P^T B-frag transform.
    // Native v_exp_f32 (no libm denorm/range fixup VALU): scores are bounded,
    // flushed denorm outputs are irrelevant to the softmax sum; -1e30 -> 0.
    union { int i[4]; short8 v; } pf[2][2];
#pragma unroll
    for (int s = 0; s < 2; ++s) {
      int pk[4][2];
#pragma unroll
      for (int nt = 0; nt < 4; ++nt) {
        float p0 = __builtin_amdgcn_exp2f(sc[s][nt][0]);
        float p1 = __builtin_amdgcn_exp2f(sc[s][nt][1]);
        float p2 = __builtin_amdgcn_exp2f(sc[s][nt][2]);
        float p3 = __builtin_amdgcn_exp2f(sc[s][nt][3]);
        rsum[s] += (p0 + p1) + (p2 + p3);
        pk[nt][0] = pkbf(p0, p1);
        pk[nt][1] = pkbf(p2, p3);
      }
      // quad-redistribution in-register:
      //   permlane32_swap(A,C): A'=[a@q0,a@q1,c@q0,c@q1] C'=[a@q2,a@q3,c@q2,c@q3]
      //   permlane16_swap(A',C'): A''=[a@q0,a@q2,c@q0,c@q2]=i[0]
      //                           C''=[a@q1,a@q3,c@q1,c@q3]=i[2]
#pragma unroll
      for (int t = 0; t < 2; ++t) {
        int A = pk[t * 2][0], C = pk[t * 2 + 1][0];
        int B2 = pk[t * 2][1], D = pk[t * 2 + 1][1];
        asm("v_permlane32_swap_b32 %0, %1" : "+v"(A), "+v"(C));
        asm("v_permlane16_swap_b32 %0, %1" : "+v"(A), "+v"(C));
        asm("v_permlane32_swap_b32 %0, %1" : "+v"(B2), "+v"(D));
        asm("v_permlane16_swap_b32 %0, %1" : "+v"(B2), "+v"(D));
        pf[s][t].i[0] = A;
        pf[s][t].i[1] = B2;
        pf[s][t].i[2] = C;
        pf[s][t].i[3] = D;
      }
    }

    // O^T += V^T P^T (V A-frags shared across strips)
    __builtin_amdgcn_s_setprio(1);
#pragma unroll
    for (int ntd = 0; ntd < 4; ++ntd) {
      short8 v0 = *(const short8*)(Vb + (ntd * 16 + l16) * 64 + ((quad ^ l7) << 3));
      short8 v1 = *(const short8*)(Vb + (ntd * 16 + l16) * 64 + (((4 + quad) ^ l7) << 3));
#pragma unroll
      for (int s = 0; s < 2; ++s) {
        o[ntd][s] = __builtin_amdgcn_mfma_f32_16x16x32_bf16(v0, pf[s][0].v, o[ntd][s], 0, 0, 0);
        o[ntd][s] = __builtin_amdgcn_mfma_f32_16x16x32_bf16(v1, pf[s][1].v, o[ntd][s], 0, 0, 0);
      }
    }
    __builtin_amdgcn_s_setprio(0);
  }

  // l reduction over quads (linear softmax base -> once at the end)
#pragma unroll
  for (int s = 0; s < 2; ++s) {
    rsum[s] += __shfl_xor(rsum[s], 16, 64);
    rsum[s] += __shfl_xor(rsum[s], 32, 64);
  }

  // epilogue: O^T -> LDS transpose -> coalesced stores
  __syncthreads();
  unsigned short* Os = smem;  // [128 q][72]
#pragma unroll
  for (int s = 0; s < 2; ++s) {
    float invl = 1.0f / rsum[s];
#pragma unroll
    for (int ntd = 0; ntd < 4; ++ntd) {
      us4 pk4;
#pragma unroll
      for (int r = 0; r < 4; ++r) pk4[r] = f2bf(o[ntd][s][r] * invl);
      *(us4*)(Os + (wave * 32 + s * 16 + l16) * 72 + ntd * 16 + quad * 4) = pk4;
    }
  }
  __syncthreads();
  const int b = bh >> 4, h = bh & 15;
#pragma unroll
  for (int it = 0; it < 4; ++it) {
    int e = it * 256 + tid;
    int row = e >> 3, c = (e & 7) * 8;
    short8 vrow = *(const short8*)(Os + row * 72 + c);
    *(short8*)(ctx + (size_t)(b * S_LEN + q0 + row) * D_MODEL + h * HEAD_DIM + c) = vrow;
  }
}

// ---------- launch ----------
extern "C" void kernel_launch(void* const* d_in, const int* in_sizes, int n_in,
                              void* d_out, int out_size, void* d_ws, size_t ws_size,
                              hipStream_t stream) {
  (void)in_sizes; (void)n_in; (void)out_size;
  const float* q  = (const float*)d_in[0];
  const float* k  = (const float*)d_in[1];
  const float* v  = (const float*)d_in[2];
  const float* Wq = (const float*)d_in[4];
  const float* bq = (const float*)d_in[5];
  const float* Wk = (const float*)d_in[6];
  const float* bk = (const float*)d_in[7];
  const float* Wv = (const float*)d_in[8];
  const float* bv = (const float*)d_in[9];
  const float* Wo = (const float*)d_in[10];
  const float* bo = (const float*)d_in[11];
  float* out = (float*)d_out;

  if (ws_size < 109051904u) return;
  char* ws = (char*)d_ws;
  unsigned short* xq    = (unsigned short*)(ws);
  unsigned short* xk    = (unsigned short*)(ws + 16777216);
  unsigned short* xv    = (unsigned short*)(ws + 33554432);
  unsigned short* wqkvT = (unsigned short*)(ws + 50331648);  // [3072][1024] = 6 MB
  unsigned short* woT   = (unsigned short*)(ws + 56623104);
  unsigned short* qh    = (unsigned short*)(ws + 58720256);
  unsigned short* kh    = qh + 8388608;
  unsigned short* vt    = kh + 8388608;  // [B,H,64,S] written directly by proj<0>
  unsigned short* ctx   = xq;            // xq dead after QKV projection

  cvt3_kernel<<<12288, 256, 0, stream>>>(q, k, v, xq, xk, xv);
  transpose_w4<<<dim3(16, 16, 4), 256, 0, stream>>>(Wq, Wk, Wv, Wo, wqkvT, woT);
  // fused QKV projection; Q scale folds 1/sqrt(64) and log2(e)
  proj_gemm<0><<<dim3(24, 64), 256, 0, stream>>>(xq, xk, xv, wqkvT, bq, bk, bv,
                                                 qh, kh, vt, 0.125f * 1.44269504088896f);
  flash_attn<<<dim3(16, 64), 256, 0, stream>>>(qh, kh, vt, ctx);
  proj_gemm<1><<<dim3(8, 64), 256, 0, stream>>>(ctx, ctx, ctx, woT, bo, bo, bo,
                                                out, out, out, 1.0f);
}

// Round 3
// 322.224 us; speedup vs baseline: 1.1930x; 1.0207x over previous
//
#include <hip/hip_runtime.h>

typedef __attribute__((ext_vector_type(8))) short short8;
typedef __attribute__((ext_vector_type(8))) unsigned short ushort8;
typedef __attribute__((ext_vector_type(4))) unsigned short us4;
typedef __attribute__((ext_vector_type(4))) float f32x4;
typedef __attribute__((ext_vector_type(4))) int i32x4;

#define S_LEN 2048
#define D_MODEL 1024
#define N_HEADS 16
#define HEAD_DIM 64

__device__ __forceinline__ unsigned short f2bf(float f) {
  union { float f; unsigned u; } x; x.f = f;
  unsigned r = x.u + 0x7FFFu + ((x.u >> 16) & 1u);
  return (unsigned short)(r >> 16);
}

// pack two f32 -> (bf16(a) | bf16(b)<<16), round-half-up, 3 VALU ops
__device__ __forceinline__ int pkbf(float a, float b) {
  union { float f; unsigned u; } x, y;
  x.f = a; y.f = b;
  return (int)__builtin_amdgcn_perm(y.u + 0x8000u, x.u + 0x8000u, 0x07060302u);
}

// ---------- fused fp32 -> bf16 convert for q,k,v ----------
__global__ __launch_bounds__(256) void cvt3_kernel(const float* __restrict__ a,
                                                   const float* __restrict__ b,
                                                   const float* __restrict__ c,
                                                   unsigned short* __restrict__ oa,
                                                   unsigned short* __restrict__ ob,
                                                   unsigned short* __restrict__ oc) {
  int bid = blockIdx.x;
  const float* in = (bid < 4096) ? a : (bid < 8192 ? b : c);
  unsigned short* out = (bid < 4096) ? oa : (bid < 8192 ? ob : oc);
  int i = (bid & 4095) * 256 + threadIdx.x;
  const f32x4* in4 = (const f32x4*)in;
  f32x4 x = in4[2 * i], y = in4[2 * i + 1];
  i32x4 o;
  o[0] = pkbf(x[0], x[1]);
  o[1] = pkbf(x[2], x[3]);
  o[2] = pkbf(y[0], y[1]);
  o[3] = pkbf(y[2], y[3]);
  ((i32x4*)out)[i] = o;
}

// ---------- all 4 weights: W [K][N] fp32 -> Wt [N][K] bf16, one dispatch ----------
__global__ __launch_bounds__(256) void transpose_w4(
    const float* __restrict__ Wq, const float* __restrict__ Wk,
    const float* __restrict__ Wv, const float* __restrict__ Wo,
    unsigned short* __restrict__ wqkvT, unsigned short* __restrict__ woT) {
  __shared__ float tile[64][65];
  const int z = blockIdx.z;
  const float* W = (z == 0) ? Wq : (z == 1) ? Wk : (z == 2) ? Wv : Wo;
  unsigned short* Wt = (z < 3) ? (wqkvT + (size_t)z * D_MODEL * D_MODEL) : woT;
  const int no = blockIdx.x * 64, ko = blockIdx.y * 64;
  const int tx = threadIdx.x & 63, ty = threadIdx.x >> 6;
  for (int r = ty; r < 64; r += 4)
    tile[r][tx] = W[(size_t)(ko + r) * D_MODEL + no + tx];
  __syncthreads();
  for (int r = ty; r < 64; r += 4)
    Wt[(size_t)(no + r) * D_MODEL + ko + tx] = f2bf(tile[tx][r]);
}

// ---------- 256x128x(BK=64) bf16 GEMM, tri-buffered counted-vmcnt pipeline ----------
// 8 waves (4M x 2N), per-wave 64x64 output (compute body identical to the verified
// 128x128 kernel). LDS = 3 x (A 32KB | B 16KB) = 144KB dynamic, 1 block/CU.
// Schedule per K-tile kt (2 phases t=0,1):
//   phase t: issue 3 global_load_lds staging HALF of K-tile kt+2 into buf[(kt+2)%3]
//            ds_read af[4]/bf[4] from buf[kt%3] (confirmed at previous boundary)
//            s_barrier ; setprio(1) ; 16 MFMA ; setprio(0) ; s_barrier
//   boundary: s_waitcnt vmcnt(6)  (kt+1's 6 loads confirmed; 6 newer stay in flight)
// Loads thus get a full K-tile (~2 compute phases) of flight time; vmcnt never
// drains to 0 in steady state (T3+T4). Race-safety: buf[(kt+2)%3] was last read in
// kt-1, whose ds_reads complete before kt-1's final barrier (lgkmcnt < MFMA < bar).
// MODE 0: fused QKV, N=3072; sel picks A/bias/out. MODE 1: out proj, N=1024, fp32.
template <int MODE>
__global__ __launch_bounds__(512) void proj_gemm(
    const unsigned short* __restrict__ A0,
    const unsigned short* __restrict__ A1,
    const unsigned short* __restrict__ A2,
    const unsigned short* __restrict__ Bt,
    const float* __restrict__ b0p, const float* __restrict__ b1p,
    const float* __restrict__ b2p,
    void* __restrict__ o0, void* __restrict__ o1, void* __restrict__ o2,
    float qscale) {
  extern __shared__ __align__(16) unsigned short smem_d[];  // 3 * 24576 shorts
  const int tid = threadIdx.x;
  const int wave = tid >> 6, lane = tid & 63;
  const int quad = lane >> 4, l16 = lane & 15;

  // bijective XCD-locality remap (grid: MODE0 24x32, MODE1 8x32)
  const int nlin = blockIdx.y * (MODE == 0 ? 24 : 8) + blockIdx.x;
  const int xcd = nlin & 7;
  const int j = nlin >> 3;  // MODE0: 0..95, MODE1: 0..31
  int bx_eff, by_eff;
  if (MODE == 0) {
    by_eff = xcd * 4 + ((j >> 3) & 3);   // 4 m-panels per XCD
    bx_eff = (j >> 5) * 8 + (j & 7);     // sel-major, bx fastest
  } else {
    by_eff = xcd * 4 + (j >> 3);
    bx_eff = j & 7;
  }
  const int m0 = by_eff * 256, n0 = bx_eff * 128;
  const int wm = (wave >> 1) * 64, wn = (wave & 1) * 64;

  const int sel = (MODE == 0) ? (n0 >> 10) : 0;
  const unsigned short* A = (MODE == 0) ? (sel == 0 ? A0 : sel == 1 ? A1 : A2) : A0;
  const float* bias = (MODE == 0) ? (sel == 0 ? b0p : sel == 1 ? b1p : b2p) : b0p;
  const float scale = (MODE == 0 && sel == 0) ? qscale : 1.0f;
  const int nb = (MODE == 0) ? (n0 & 1023) : n0;

  f32x4 acc[4][4] = {};

  // staging geometry: row = rd*64 + wave*8 + (lane>>3); source col chunk swizzled
  // to match the read-side XOR (row&7 == (lane>>3)&7 for every round)
  const int srw = wave * 8 + (lane >> 3);
  const int sch = ((lane & 7) ^ ((lane >> 3) & 7)) << 3;

  auto stage = [&](int kt, int half) {
    unsigned short* Ab = smem_d + (kt % 3) * 24576;
    unsigned short* Bb = Ab + 16384;
    const int k0 = kt * 64;
#pragma unroll
    for (int rr = 0; rr < 2; ++rr) {
      const int rd = half * 2 + rr;
      const unsigned short* g = A + (size_t)(m0 + rd * 64 + srw) * D_MODEL + k0 + sch;
      __builtin_amdgcn_global_load_lds((const __attribute__((address_space(1))) void*)g,
          (__attribute__((address_space(3))) void*)(Ab + rd * 4096 + wave * 512), 16, 0, 0);
    }
    const unsigned short* gb = Bt + (size_t)(n0 + half * 64 + srw) * D_MODEL + k0 + sch;
    __builtin_amdgcn_global_load_lds((const __attribute__((address_space(1))) void*)gb,
        (__attribute__((address_space(3))) void*)(Bb + half * 4096 + wave * 512), 16, 0, 0);
  };

  // prologue: kt0 + kt1 fully staged (12 loads); confirm kt0 (drain all but kt1's 6)
  stage(0, 0); stage(0, 1); stage(1, 0); stage(1, 1);
  asm volatile("s_waitcnt vmcnt(6)" ::: "memory");
  __builtin_amdgcn_s_barrier();

  for (int kt = 0; kt < 16; ++kt) {
    const unsigned short* Ab = smem_d + (kt % 3) * 24576;
    const unsigned short* Bb = Ab + 16384;
#pragma unroll
    for (int t = 0; t < 2; ++t) {
      if (kt + 2 < 16) stage(kt + 2, t);
      short8 af[4], bf[4];
#pragma unroll
      for (int i = 0; i < 4; ++i) {
        int r = wm + i * 16 + l16;
        af[i] = *(const short8*)(Ab + r * 64 + (((t * 4 + quad) ^ (r & 7)) << 3));
      }
#pragma unroll
      for (int j2 = 0; j2 < 4; ++j2) {
        int r = wn + j2 * 16 + l16;
        bf[j2] = *(const short8*)(Bb + r * 64 + (((t * 4 + quad) ^ (r & 7)) << 3));
      }
      __builtin_amdgcn_s_barrier();
      __builtin_amdgcn_s_setprio(1);
#pragma unroll
      for (int i = 0; i < 4; ++i)
#pragma unroll
        for (int j2 = 0; j2 < 4; ++j2)
          acc[i][j2] = __builtin_amdgcn_mfma_f32_16x16x32_bf16(af[i], bf[j2], acc[i][j2], 0, 0, 0);
      __builtin_amdgcn_s_setprio(0);
      __builtin_amdgcn_s_barrier();
    }
    // boundary: confirm kt+1's tile (its 6 loads were issued during kt-1)
    if (kt + 2 < 16) {
      asm volatile("s_waitcnt vmcnt(6)" ::: "memory");
    } else {
      asm volatile("s_waitcnt vmcnt(0)" ::: "memory");
    }
  }

  float bv4[4];
#pragma unroll
  for (int j2 = 0; j2 < 4; ++j2) bv4[j2] = bias[nb + wn + j2 * 16 + l16];

  if (MODE == 0) {
    if (sel < 2) {
      unsigned short* T = smem_d + wave * 1152;
      unsigned short* out = (unsigned short*)(sel == 0 ? o0 : o1);
      const int h = (nb + wn) >> 6;
#pragma unroll
      for (int i = 0; i < 4; ++i) {
#pragma unroll
        for (int j2 = 0; j2 < 4; ++j2)
#pragma unroll
          for (int r = 0; r < 4; ++r)
            T[(quad * 4 + r) * 72 + j2 * 16 + l16] = f2bf((acc[i][j2][r] + bv4[j2]) * scale);
        int m = m0 + wm + i * 16 + l16;
        int b = m >> 11, s = m & 2047;
#pragma unroll
        for (int t = 0; t < 2; ++t) {
          short8 row = *(const short8*)(T + l16 * 72 + t * 32 + quad * 8);
          *(short8*)(out + (((size_t)(b * N_HEADS + h) * S_LEN + s) << 6) + t * 32 + quad * 8) = row;
        }
      }
    } else {
      unsigned short* vt = (unsigned short*)o2;
#pragma unroll
      for (int i = 0; i < 4; ++i) {
        int m = m0 + wm + i * 16 + quad * 4;
        int b = m >> 11, s = m & 2047;
#pragma unroll
        for (int j2 = 0; j2 < 4; ++j2) {
          int n = nb + wn + j2 * 16 + l16;
          int h = n >> 6, d = n & 63;
          us4 pv;
#pragma unroll
          for (int r = 0; r < 4; ++r) pv[r] = f2bf(acc[i][j2][r] + bv4[j2]);
          *(us4*)(vt + (((size_t)(b * N_HEADS + h) * 64 + d) << 11) + s) = pv;
        }
      }
    }
  } else {
    float* Tf = (float*)smem_d + wave * 1088;
    float* out = (float*)o0;
#pragma unroll
    for (int i = 0; i < 4; ++i) {
#pragma unroll
      for (int j2 = 0; j2 < 4; ++j2)
#pragma unroll
        for (int r = 0; r < 4; ++r)
          Tf[(quad * 4 + r) * 68 + j2 * 16 + l16] = acc[i][j2][r] + bv4[j2];
      int m = m0 + wm + i * 16 + l16;
#pragma unroll
      for (int t = 0; t < 4; ++t) {
        f32x4 row = *(const f32x4*)(Tf + l16 * 68 + t * 16 + quad * 4);
        *(f32x4*)(out + (size_t)m * D_MODEL + nb + wn + t * 16 + quad * 4) = row;
      }
    }
  }
}

// ---------- causal flash attention: R3 q-split structure + 128-q blocks + K/V dbuf ----------
// Q pre-scaled by 0.125*log2(e). Block owns 128 queries (qi*128..); wave owns 32
// (2 strips of 16). K/V staged per 64-key tile, double-buffered; stage(kt+1) is
// issued AFTER the top-of-loop barrier so the barrier's vmcnt(0) drain only waits
// on loads issued a full compute-phase earlier. K/V frag reads shared across strips.
// P^T B-frag transform via v_permlane{32,16}_swap (VALU pipe, no LDS traffic).
// T1 remap: 8 heads pinned per XCD; the 4 co-resident blocks on a CU are the SAME
// head (shared K/V stream -> L2/L1 hits on the stage loads) with qi values
// summing to a constant for causal load balance.
__global__ __launch_bounds__(256, 4) void flash_attn(
    const unsigned short* __restrict__ Qh,  // [B,H,S,64] bf16 (scaled)
    const unsigned short* __restrict__ Kh,  // [B,H,S,64] bf16
    const unsigned short* __restrict__ Vt,  // [B,H,64,S] bf16
    unsigned short* __restrict__ ctx) {     // [B,S,1024] bf16
  __shared__ __align__(16) unsigned short smem[16384];  // 32 KB: 2 x (K 8KB | V 8KB)
  const int tid = threadIdx.x;
  const int wave = tid >> 6, lane = tid & 63;
  const int quad = lane >> 4, l16 = lane & 15;
  const int l7 = l16 & 7;

  // bijective head/XCD remap: n = (qslot<<6) | (hg<<3) | xcd, bh = xcd*8+hg
  const int nlin = blockIdx.y * 16 + blockIdx.x;
  const int xcd = nlin & 7;
  const int rr = nlin >> 3;            // 0..127
  const int bh = xcd * 8 + (rr & 7);   // 8 heads per XCD
  const int qslot = rr >> 3;           // 0..15
  const int qa = qslot & 3, qb = qslot >> 2;
  const int qbase = qa + ((qb >> 1) << 2);
  const int qi = (qb & 1) ? (15 - qbase) : qbase;
  const int q0 = qi * 128;
  const int nk = 2 * qi + 2;
  const size_t hb = (size_t)bh * (S_LEN * HEAD_DIM);
  const int srow = lane >> 3;
  const int schunk = ((lane & 7) ^ srow) * 8;

  auto stage = [&](int kt, int buf) {
    unsigned short* Kb = smem + buf * 8192;
    unsigned short* Vb = smem + buf * 8192 + 4096;
#pragma unroll
    for (int c = 0; c < 2; ++c) {
      int row = wave * 16 + c * 8 + srow;
      const unsigned short* gk = Kh + hb + (size_t)(kt * 64 + row) * 64 + schunk;
      __builtin_amdgcn_global_load_lds((const __attribute__((address_space(1))) void*)gk,
          (__attribute__((address_space(3))) void*)(Kb + (wave * 16 + c * 8) * 64), 16, 0, 0);
      const unsigned short* gv = Vt + hb + (size_t)row * S_LEN + kt * 64 + schunk;
      __builtin_amdgcn_global_load_lds((const __attribute__((address_space(1))) void*)gv,
          (__attribute__((address_space(3))) void*)(Vb + (wave * 16 + c * 8) * 64), 16, 0, 0);
    }
  };

  stage(0, 0);

  // Q B-fragments for both strips, register-resident (coalesced global reads)
  short8 qf[2][2];
#pragma unroll
  for (int s = 0; s < 2; ++s)
#pragma unroll
    for (int t = 0; t < 2; ++t)
      qf[s][t] = *(const short8*)(Qh + hb +
          (size_t)(q0 + wave * 32 + s * 16 + l16) * 64 + t * 32 + quad * 8);

  f32x4 o[4][2] = {};  // o[ntd][s]: d=ntd*16+quad*4+r, query=strip s col l16
  float rsum[2] = {0.f, 0.f};

  for (int kt = 0; kt < nk; ++kt) {
    __syncthreads();  // drains stage issued last iteration; buf[kt&1] now ready
    if (kt + 1 < nk) stage(kt + 1, (kt + 1) & 1);
    const unsigned short* Kb = smem + (kt & 1) * 8192;
    const unsigned short* Vb = Kb + 4096;

    // wave-uniform skip: all keys of this tile beyond wave's max query
    if (kt * 64 > q0 + wave * 32 + 31) continue;

    // S^T = K Q^T per strip (K A-frags shared across strips)
    f32x4 sc[2][4];
    __builtin_amdgcn_s_setprio(1);
#pragma unroll
    for (int nt = 0; nt < 4; ++nt) {
      short8 k0 = *(const short8*)(Kb + (nt * 16 + l16) * 64 + ((quad ^ l7) << 3));
      short8 k1 = *(const short8*)(Kb + (nt * 16 + l16) * 64 + (((4 + quad) ^ l7) << 3));
#pragma unroll
      for (int s = 0; s < 2; ++s) {
        f32x4 z = {};
        z = __builtin_amdgcn_mfma_f32_16x16x32_bf16(k0, qf[s][0], z, 0, 0, 0);
        sc[s][nt] = __builtin_amdgcn_mfma_f32_16x16x32_bf16(k1, qf[s][1], z, 0, 0, 0);
      }
    }
    __builtin_amdgcn_s_setprio(0);
    if (kt >= 2 * qi) {  // only the last two tiles can touch the diagonal
#pragma unroll
      for (int s = 0; s < 2; ++s) {
        int qg = q0 + wave * 32 + s * 16 + l16;
#pragma unroll
        for (int nt = 0; nt < 4; ++nt) {
          int kg = kt * 64 + nt * 16 + quad * 4;
#pragma unroll
          for (int r = 0; r < 4; ++r)
            if (kg + r > qg) sc[s][nt][r] = -1e30f;
        }
      }
    }

    // fixed-base softmax numerator + P^T B-frag transform.
    union { int i[4]; short8 v; } pf[2][2];
#pragma unroll
    for (int s = 0; s < 2; ++s) {
      int pk[4][2];
#pragma unroll
      for (int nt = 0; nt < 4; ++nt) {
        float p0 = __builtin_amdgcn_exp2f(sc[s][nt][0]);
        float p1 = __builtin_amdgcn_exp2f(sc[s][nt][1]);
        float p2 = __builtin_amdgcn_exp2f(sc[s][nt][2]);
        float p3 = __builtin_amdgcn_exp2f(sc[s][nt][3]);
        rsum[s] += (p0 + p1) + (p2 + p3);
        pk[nt][0] = pkbf(p0, p1);
        pk[nt][1] = pkbf(p2, p3);
      }
      // quad-redistribution in-register:
      //   permlane32_swap(A,C): A'=[a@q0,a@q1,c@q0,c@q1] C'=[a@q2,a@q3,c@q2,c@q3]
      //   permlane16_swap(A',C'): A''=[a@q0,a@q2,c@q0,c@q2]=i[0]
      //                           C''=[a@q1,a@q3,c@q1,c@q3]=i[2]
#pragma unroll
      for (int t = 0; t < 2; ++t) {
        int A = pk[t * 2][0], C = pk[t * 2 + 1][0];
        int B2 = pk[t * 2][1], D = pk[t * 2 + 1][1];
        asm("v_permlane32_swap_b32 %0, %1" : "+v"(A), "+v"(C));
        asm("v_permlane16_swap_b32 %0, %1" : "+v"(A), "+v"(C));
        asm("v_permlane32_swap_b32 %0, %1" : "+v"(B2), "+v"(D));
        asm("v_permlane16_swap_b32 %0, %1" : "+v"(B2), "+v"(D));
        pf[s][t].i[0] = A;
        pf[s][t].i[1] = B2;
        pf[s][t].i[2] = C;
        pf[s][t].i[3] = D;
      }
    }

    // O^T += V^T P^T (V A-frags shared across strips)
    __builtin_amdgcn_s_setprio(1);
#pragma unroll
    for (int ntd = 0; ntd < 4; ++ntd) {
      short8 v0 = *(const short8*)(Vb + (ntd * 16 + l16) * 64 + ((quad ^ l7) << 3));
      short8 v1 = *(const short8*)(Vb + (ntd * 16 + l16) * 64 + (((4 + quad) ^ l7) << 3));
#pragma unroll
      for (int s = 0; s < 2; ++s) {
        o[ntd][s] = __builtin_amdgcn_mfma_f32_16x16x32_bf16(v0, pf[s][0].v, o[ntd][s], 0, 0, 0);
        o[ntd][s] = __builtin_amdgcn_mfma_f32_16x16x32_bf16(v1, pf[s][1].v, o[ntd][s], 0, 0, 0);
      }
    }
    __builtin_amdgcn_s_setprio(0);
  }

  // l reduction over quads (linear softmax base -> once at the end)
#pragma unroll
  for (int s = 0; s < 2; ++s) {
    rsum[s] += __shfl_xor(rsum[s], 16, 64);
    rsum[s] += __shfl_xor(rsum[s], 32, 64);
  }

  // epilogue: O^T -> LDS transpose -> coalesced stores
  __syncthreads();
  unsigned short* Os = smem;  // [128 q][72]
#pragma unroll
  for (int s = 0; s < 2; ++s) {
    float invl = 1.0f / rsum[s];
#pragma unroll
    for (int ntd = 0; ntd < 4; ++ntd) {
      us4 pk4;
#pragma unroll
      for (int r = 0; r < 4; ++r) pk4[r] = f2bf(o[ntd][s][r] * invl);
      *(us4*)(Os + (wave * 32 + s * 16 + l16) * 72 + ntd * 16 + quad * 4) = pk4;
    }
  }
  __syncthreads();
  const int b = bh >> 4, h = bh & 15;
#pragma unroll
  for (int it = 0; it < 4; ++it) {
    int e = it * 256 + tid;
    int row = e >> 3, c = (e & 7) * 8;
    short8 vrow = *(const short8*)(Os + row * 72 + c);
    *(short8*)(ctx + (size_t)(b * S_LEN + q0 + row) * D_MODEL + h * HEAD_DIM + c) = vrow;
  }
}

// ---------- launch ----------
extern "C" void kernel_launch(void* const* d_in, const int* in_sizes, int n_in,
                              void* d_out, int out_size, void* d_ws, size_t ws_size,
                              hipStream_t stream) {
  (void)in_sizes; (void)n_in; (void)out_size;
  const float* q  = (const float*)d_in[0];
  const float* k  = (const float*)d_in[1];
  const float* v  = (const float*)d_in[2];
  const float* Wq = (const float*)d_in[4];
  const float* bq = (const float*)d_in[5];
  const float* Wk = (const float*)d_in[6];
  const float* bk = (const float*)d_in[7];
  const float* Wv = (const float*)d_in[8];
  const float* bv = (const float*)d_in[9];
  const float* Wo = (const float*)d_in[10];
  const float* bo = (const float*)d_in[11];
  float* out = (float*)d_out;

  if (ws_size < 109051904u) return;
  char* ws = (char*)d_ws;
  unsigned short* xq    = (unsigned short*)(ws);
  unsigned short* xk    = (unsigned short*)(ws + 16777216);
  unsigned short* xv    = (unsigned short*)(ws + 33554432);
  unsigned short* wqkvT = (unsigned short*)(ws + 50331648);  // [3072][1024] = 6 MB
  unsigned short* woT   = (unsigned short*)(ws + 56623104);
  unsigned short* qh    = (unsigned short*)(ws + 58720256);
  unsigned short* kh    = qh + 8388608;
  unsigned short* vt    = kh + 8388608;  // [B,H,64,S] written directly by proj<0>
  unsigned short* ctx   = xq;            // xq dead after QKV projection

  static int attr_done = 0;
  if (!attr_done) {
    auto* k0f = proj_gemm<0>;
    auto* k1f = proj_gemm<1>;
    hipFuncSetAttribute(reinterpret_cast<const void*>(k0f),
                        hipFuncAttributeMaxDynamicSharedMemorySize, 147456);
    hipFuncSetAttribute(reinterpret_cast<const void*>(k1f),
                        hipFuncAttributeMaxDynamicSharedMemorySize, 147456);
    attr_done = 1;
  }

  cvt3_kernel<<<12288, 256, 0, stream>>>(q, k, v, xq, xk, xv);
  transpose_w4<<<dim3(16, 16, 4), 256, 0, stream>>>(Wq, Wk, Wv, Wo, wqkvT, woT);
  // fused QKV projection; Q scale folds 1/sqrt(64) and log2(e)
  proj_gemm<0><<<dim3(24, 32), 512, 147456, stream>>>(xq, xk, xv, wqkvT, bq, bk, bv,
                                                      qh, kh, vt, 0.125f * 1.44269504088896f);
  flash_attn<<<dim3(16, 64), 256, 0, stream>>>(qh, kh, vt, ctx);
  proj_gemm<1><<<dim3(8, 32), 512, 147456, stream>>>(ctx, ctx, ctx, woT, bo, bo, bo,
                                                     out, out, out, 1.0f);
}

// Round 4
// 319.518 us; speedup vs baseline: 1.2031x; 1.0085x over previous
//
#include <hip/hip_runtime.h>

typedef __attribute__((ext_vector_type(8))) short short8;
typedef __attribute__((ext_vector_type(8))) unsigned short ushort8;
typedef __attribute__((ext_vector_type(4))) unsigned short us4;
typedef __attribute__((ext_vector_type(4))) float f32x4;
typedef __attribute__((ext_vector_type(4))) int i32x4;

#define S_LEN 2048
#define D_MODEL 1024
#define N_HEADS 16
#define HEAD_DIM 64

__device__ __forceinline__ unsigned short f2bf(float f) {
  union { float f; unsigned u; } x; x.f = f;
  unsigned r = x.u + 0x7FFFu + ((x.u >> 16) & 1u);
  return (unsigned short)(r >> 16);
}

// pack two f32 -> (bf16(a) | bf16(b)<<16), round-half-up, 3 VALU ops
__device__ __forceinline__ int pkbf(float a, float b) {
  union { float f; unsigned u; } x, y;
  x.f = a; y.f = b;
  return (int)__builtin_amdgcn_perm(y.u + 0x8000u, x.u + 0x8000u, 0x07060302u);
}

// ---------- fused fp32 -> bf16 convert for q,k,v ----------
__global__ __launch_bounds__(256) void cvt3_kernel(const float* __restrict__ a,
                                                   const float* __restrict__ b,
                                                   const float* __restrict__ c,
                                                   unsigned short* __restrict__ oa,
                                                   unsigned short* __restrict__ ob,
                                                   unsigned short* __restrict__ oc) {
  int bid = blockIdx.x;
  const float* in = (bid < 4096) ? a : (bid < 8192 ? b : c);
  unsigned short* out = (bid < 4096) ? oa : (bid < 8192 ? ob : oc);
  int i = (bid & 4095) * 256 + threadIdx.x;
  const f32x4* in4 = (const f32x4*)in;
  f32x4 x = in4[2 * i], y = in4[2 * i + 1];
  i32x4 o;
  o[0] = pkbf(x[0], x[1]);
  o[1] = pkbf(x[2], x[3]);
  o[2] = pkbf(y[0], y[1]);
  o[3] = pkbf(y[2], y[3]);
  ((i32x4*)out)[i] = o;
}

// ---------- all 4 weights: W [K][N] fp32 -> Wt [N][K] bf16, one dispatch ----------
__global__ __launch_bounds__(256) void transpose_w4(
    const float* __restrict__ Wq, const float* __restrict__ Wk,
    const float* __restrict__ Wv, const float* __restrict__ Wo,
    unsigned short* __restrict__ wqkvT, unsigned short* __restrict__ woT) {
  __shared__ float tile[64][65];
  const int z = blockIdx.z;
  const float* W = (z == 0) ? Wq : (z == 1) ? Wk : (z == 2) ? Wv : Wo;
  unsigned short* Wt = (z < 3) ? (wqkvT + (size_t)z * D_MODEL * D_MODEL) : woT;
  const int no = blockIdx.x * 64, ko = blockIdx.y * 64;
  const int tx = threadIdx.x & 63, ty = threadIdx.x >> 6;
  for (int r = ty; r < 64; r += 4)
    tile[r][tx] = W[(size_t)(ko + r) * D_MODEL + no + tx];
  __syncthreads();
  for (int r = ty; r < 64; r += 4)
    Wt[(size_t)(no + r) * D_MODEL + ko + tx] = f2bf(tile[tx][r]);
}

// ---------- 256x128x(BK=64) bf16 GEMM, tri-buffered, fully software-pipelined ----------
// 8 waves (4M x 2N), per-wave 64x64. LDS = 3 x 48KB = 144KB dynamic, 1 block/CU.
// Flat 32-phase schedule (phase p: kt=p>>1, t=p&1), ONE barrier per phase:
//   stage half(p+4)                      (global_load_lds, 2 K-tiles ahead)
//   ds_read fragment regs for phase p+1  (hidden under this phase's MFMA)
//   setprio(1); 16 MFMA on phase-p regs; setprio(0)
//   [end of even phase] vmcnt(3)         (confirms kt+1 landed; 1 half in flight)
//   s_barrier; sched_barrier(0)
// RAW safety: buf[kt+1] confirmed by vmcnt+barrier BEFORE any wave preloads it
// (barrier-ordered, not timing-based). WAR safety: stage(kt+2) overwrites
// buf[kt-1]; its last ds_reads completed before kt-1's odd MFMA, which precedes
// the end-of-phase barrier that precedes this stage.
// MODE 0: fused QKV, N=3072; sel picks A/bias/out. MODE 1: out proj, N=1024, fp32.
template <int MODE>
__global__ __launch_bounds__(512) void proj_gemm(
    const unsigned short* __restrict__ A0,
    const unsigned short* __restrict__ A1,
    const unsigned short* __restrict__ A2,
    const unsigned short* __restrict__ Bt,
    const float* __restrict__ b0p, const float* __restrict__ b1p,
    const float* __restrict__ b2p,
    void* __restrict__ o0, void* __restrict__ o1, void* __restrict__ o2,
    float qscale) {
  extern __shared__ __align__(16) unsigned short smem_d[];  // 3 * 24576 shorts
  const int tid = threadIdx.x;
  const int wave = tid >> 6, lane = tid & 63;
  const int quad = lane >> 4, l16 = lane & 15;

  // bijective XCD-locality remap (grid: MODE0 24x32, MODE1 8x32)
  const int nlin = blockIdx.y * (MODE == 0 ? 24 : 8) + blockIdx.x;
  const int xcd = nlin & 7;
  const int j = nlin >> 3;  // MODE0: 0..95, MODE1: 0..31
  int bx_eff, by_eff;
  if (MODE == 0) {
    by_eff = xcd * 4 + ((j >> 3) & 3);   // 4 m-panels per XCD
    bx_eff = (j >> 5) * 8 + (j & 7);     // sel-major, bx fastest
  } else {
    by_eff = xcd * 4 + (j >> 3);
    bx_eff = j & 7;
  }
  const int m0 = by_eff * 256, n0 = bx_eff * 128;
  const int wm = (wave >> 1) * 64, wn = (wave & 1) * 64;

  const int sel = (MODE == 0) ? (n0 >> 10) : 0;
  const unsigned short* A = (MODE == 0) ? (sel == 0 ? A0 : sel == 1 ? A1 : A2) : A0;
  const float* bias = (MODE == 0) ? (sel == 0 ? b0p : sel == 1 ? b1p : b2p) : b0p;
  const float scale = (MODE == 0 && sel == 0) ? qscale : 1.0f;
  const int nb = (MODE == 0) ? (n0 & 1023) : n0;

  f32x4 acc[4][4] = {};

  // staging geometry: row = rd*64 + wave*8 + (lane>>3); source col chunk swizzled
  // to match the read-side XOR (row&7 == (lane>>3)&7 for every round)
  const int srw = wave * 8 + (lane >> 3);
  const int sch = ((lane & 7) ^ ((lane >> 3) & 7)) << 3;

  auto stage = [&](int kt, int half) {
    unsigned short* Ab = smem_d + (kt % 3) * 24576;
    unsigned short* Bb = Ab + 16384;
    const int k0 = kt * 64;
#pragma unroll
    for (int rr = 0; rr < 2; ++rr) {
      const int rd = half * 2 + rr;
      const unsigned short* g = A + (size_t)(m0 + rd * 64 + srw) * D_MODEL + k0 + sch;
      __builtin_amdgcn_global_load_lds((const __attribute__((address_space(1))) void*)g,
          (__attribute__((address_space(3))) void*)(Ab + rd * 4096 + wave * 512), 16, 0, 0);
    }
    const unsigned short* gb = Bt + (size_t)(n0 + half * 64 + srw) * D_MODEL + k0 + sch;
    __builtin_amdgcn_global_load_lds((const __attribute__((address_space(1))) void*)gb,
        (__attribute__((address_space(3))) void*)(Bb + half * 4096 + wave * 512), 16, 0, 0);
  };

  auto preload = [&](short8* af, short8* bf, const unsigned short* Ab,
                     const unsigned short* Bb, int t) {
#pragma unroll
    for (int i = 0; i < 4; ++i) {
      int r = wm + i * 16 + l16;
      af[i] = *(const short8*)(Ab + r * 64 + (((t * 4 + quad) ^ (r & 7)) << 3));
    }
#pragma unroll
    for (int j2 = 0; j2 < 4; ++j2) {
      int r = wn + j2 * 16 + l16;
      bf[j2] = *(const short8*)(Bb + r * 64 + (((t * 4 + quad) ^ (r & 7)) << 3));
    }
  };

  auto mfma16 = [&](const short8* af, const short8* bf) {
#pragma unroll
    for (int i = 0; i < 4; ++i)
#pragma unroll
      for (int j2 = 0; j2 < 4; ++j2)
        acc[i][j2] = __builtin_amdgcn_mfma_f32_16x16x32_bf16(af[i], bf[j2], acc[i][j2], 0, 0, 0);
  };

  // prologue: kt0 + kt1 fully staged (12 loads); confirm kt0 (6 of kt1 in flight)
  stage(0, 0); stage(0, 1); stage(1, 0); stage(1, 1);
  asm volatile("s_waitcnt vmcnt(6)" ::: "memory");
  __builtin_amdgcn_s_barrier();
  __builtin_amdgcn_sched_barrier(0);

  short8 afA[4], bfA[4], afB[4], bfB[4];
  preload(afA, bfA, smem_d, smem_d + 16384, 0);  // phase 0 regs

  for (int kt = 0; kt < 16; ++kt) {
    const unsigned short* Ab = smem_d + (kt % 3) * 24576;
    const unsigned short* Bb = Ab + 16384;
    const unsigned short* An = smem_d + ((kt + 1) % 3) * 24576;
    const unsigned short* Bn = An + 16384;

    // ---- even phase (p = 2kt): MFMA regs A, preload regs B (same kt, t=1)
    if (kt + 2 < 16) stage(kt + 2, 0);
    preload(afB, bfB, Ab, Bb, 1);
    __builtin_amdgcn_s_setprio(1);
    mfma16(afA, bfA);
    __builtin_amdgcn_s_setprio(0);
    if (kt + 2 < 16) {
      asm volatile("s_waitcnt vmcnt(3)" ::: "memory");  // kt+1 fully landed
    } else if (kt + 1 < 16) {
      asm volatile("s_waitcnt vmcnt(0)" ::: "memory");
    }
    __builtin_amdgcn_s_barrier();
    __builtin_amdgcn_sched_barrier(0);

    // ---- odd phase (p = 2kt+1): MFMA regs B, preload regs A (kt+1, t=0)
    if (2 * kt + 5 < 32) stage(kt + 2, 1);
    if (kt + 1 < 16) preload(afA, bfA, An, Bn, 0);
    __builtin_amdgcn_s_setprio(1);
    mfma16(afB, bfB);
    __builtin_amdgcn_s_setprio(0);
    __builtin_amdgcn_s_barrier();
    __builtin_amdgcn_sched_barrier(0);
  }

  float bv4[4];
#pragma unroll
  for (int j2 = 0; j2 < 4; ++j2) bv4[j2] = bias[nb + wn + j2 * 16 + l16];

  if (MODE == 0) {
    if (sel < 2) {
      unsigned short* T = smem_d + wave * 1152;
      unsigned short* out = (unsigned short*)(sel == 0 ? o0 : o1);
      const int h = (nb + wn) >> 6;
#pragma unroll
      for (int i = 0; i < 4; ++i) {
#pragma unroll
        for (int j2 = 0; j2 < 4; ++j2)
#pragma unroll
          for (int r = 0; r < 4; ++r)
            T[(quad * 4 + r) * 72 + j2 * 16 + l16] = f2bf((acc[i][j2][r] + bv4[j2]) * scale);
        int m = m0 + wm + i * 16 + l16;
        int b = m >> 11, s = m & 2047;
#pragma unroll
        for (int t = 0; t < 2; ++t) {
          short8 row = *(const short8*)(T + l16 * 72 + t * 32 + quad * 8);
          *(short8*)(out + (((size_t)(b * N_HEADS + h) * S_LEN + s) << 6) + t * 32 + quad * 8) = row;
        }
      }
    } else {
      unsigned short* vt = (unsigned short*)o2;
#pragma unroll
      for (int i = 0; i < 4; ++i) {
        int m = m0 + wm + i * 16 + quad * 4;
        int b = m >> 11, s = m & 2047;
#pragma unroll
        for (int j2 = 0; j2 < 4; ++j2) {
          int n = nb + wn + j2 * 16 + l16;
          int h = n >> 6, d = n & 63;
          us4 pv;
#pragma unroll
          for (int r = 0; r < 4; ++r) pv[r] = f2bf(acc[i][j2][r] + bv4[j2]);
          *(us4*)(vt + (((size_t)(b * N_HEADS + h) * 64 + d) << 11) + s) = pv;
        }
      }
    }
  } else {
    float* Tf = (float*)smem_d + wave * 1088;
    float* out = (float*)o0;
#pragma unroll
    for (int i = 0; i < 4; ++i) {
#pragma unroll
      for (int j2 = 0; j2 < 4; ++j2)
#pragma unroll
        for (int r = 0; r < 4; ++r)
          Tf[(quad * 4 + r) * 68 + j2 * 16 + l16] = acc[i][j2][r] + bv4[j2];
      int m = m0 + wm + i * 16 + l16;
#pragma unroll
      for (int t = 0; t < 4; ++t) {
        f32x4 row = *(const f32x4*)(Tf + l16 * 68 + t * 16 + quad * 4);
        *(f32x4*)(out + (size_t)m * D_MODEL + nb + wn + t * 16 + quad * 4) = row;
      }
    }
  }
}

// ---------- causal flash attention: R3 q-split structure + 128-q blocks + K/V dbuf ----------
// Q pre-scaled by 0.125*log2(e). Block owns 128 queries (qi*128..); wave owns 32
// (2 strips of 16). K/V staged per 64-key tile, double-buffered; stage(kt+1) is
// issued AFTER the top-of-loop barrier so the barrier's vmcnt(0) drain only waits
// on loads issued a full compute-phase earlier. K/V frag reads shared across strips.
// P^T B-frag transform via v_permlane{32,16}_swap (VALU pipe, no LDS traffic).
// T1 remap: 8 heads pinned per XCD; the 4 co-resident blocks on a CU are the SAME
// head (shared K/V stream -> L2/L1 hits on the stage loads) with qi values
// summing to a constant for causal load balance.
__global__ __launch_bounds__(256, 4) void flash_attn(
    const unsigned short* __restrict__ Qh,  // [B,H,S,64] bf16 (scaled)
    const unsigned short* __restrict__ Kh,  // [B,H,S,64] bf16
    const unsigned short* __restrict__ Vt,  // [B,H,64,S] bf16
    unsigned short* __restrict__ ctx) {     // [B,S,1024] bf16
  __shared__ __align__(16) unsigned short smem[16384];  // 32 KB: 2 x (K 8KB | V 8KB)
  const int tid = threadIdx.x;
  const int wave = tid >> 6, lane = tid & 63;
  const int quad = lane >> 4, l16 = lane & 15;
  const int l7 = l16 & 7;

  // bijective head/XCD remap: n = (qslot<<6) | (hg<<3) | xcd, bh = xcd*8+hg
  const int nlin = blockIdx.y * 16 + blockIdx.x;
  const int xcd = nlin & 7;
  const int rr = nlin >> 3;            // 0..127
  const int bh = xcd * 8 + (rr & 7);   // 8 heads per XCD
  const int qslot = rr >> 3;           // 0..15
  const int qa = qslot & 3, qb = qslot >> 2;
  const int qbase = qa + ((qb >> 1) << 2);
  const int qi = (qb & 1) ? (15 - qbase) : qbase;
  const int q0 = qi * 128;
  const int nk = 2 * qi + 2;
  const size_t hb = (size_t)bh * (S_LEN * HEAD_DIM);
  const int srow = lane >> 3;
  const int schunk = ((lane & 7) ^ srow) * 8;

  auto stage = [&](int kt, int buf) {
    unsigned short* Kb = smem + buf * 8192;
    unsigned short* Vb = smem + buf * 8192 + 4096;
#pragma unroll
    for (int c = 0; c < 2; ++c) {
      int row = wave * 16 + c * 8 + srow;
      const unsigned short* gk = Kh + hb + (size_t)(kt * 64 + row) * 64 + schunk;
      __builtin_amdgcn_global_load_lds((const __attribute__((address_space(1))) void*)gk,
          (__attribute__((address_space(3))) void*)(Kb + (wave * 16 + c * 8) * 64), 16, 0, 0);
      const unsigned short* gv = Vt + hb + (size_t)row * S_LEN + kt * 64 + schunk;
      __builtin_amdgcn_global_load_lds((const __attribute__((address_space(1))) void*)gv,
          (__attribute__((address_space(3))) void*)(Vb + (wave * 16 + c * 8) * 64), 16, 0, 0);
    }
  };

  stage(0, 0);

  // Q B-fragments for both strips, register-resident (coalesced global reads)
  short8 qf[2][2];
#pragma unroll
  for (int s = 0; s < 2; ++s)
#pragma unroll
    for (int t = 0; t < 2; ++t)
      qf[s][t] = *(const short8*)(Qh + hb +
          (size_t)(q0 + wave * 32 + s * 16 + l16) * 64 + t * 32 + quad * 8);

  f32x4 o[4][2] = {};  // o[ntd][s]: d=ntd*16+quad*4+r, query=strip s col l16
  float rsum[2] = {0.f, 0.f};

  for (int kt = 0; kt < nk; ++kt) {
    __syncthreads();  // drains stage issued last iteration; buf[kt&1] now ready
    if (kt + 1 < nk) stage(kt + 1, (kt + 1) & 1);
    const unsigned short* Kb = smem + (kt & 1) * 8192;
    const unsigned short* Vb = Kb + 4096;

    // wave-uniform skip: all keys of this tile beyond wave's max query
    if (kt * 64 > q0 + wave * 32 + 31) continue;

    // S^T = K Q^T per strip (K A-frags shared across strips)
    f32x4 sc[2][4];
    __builtin_amdgcn_s_setprio(1);
#pragma unroll
    for (int nt = 0; nt < 4; ++nt) {
      short8 k0 = *(const short8*)(Kb + (nt * 16 + l16) * 64 + ((quad ^ l7) << 3));
      short8 k1 = *(const short8*)(Kb + (nt * 16 + l16) * 64 + (((4 + quad) ^ l7) << 3));
#pragma unroll
      for (int s = 0; s < 2; ++s) {
        f32x4 z = {};
        z = __builtin_amdgcn_mfma_f32_16x16x32_bf16(k0, qf[s][0], z, 0, 0, 0);
        sc[s][nt] = __builtin_amdgcn_mfma_f32_16x16x32_bf16(k1, qf[s][1], z, 0, 0, 0);
      }
    }
    __builtin_amdgcn_s_setprio(0);
    if (kt >= 2 * qi) {  // only the last two tiles can touch the diagonal
#pragma unroll
      for (int s = 0; s < 2; ++s) {
        int qg = q0 + wave * 32 + s * 16 + l16;
#pragma unroll
        for (int nt = 0; nt < 4; ++nt) {
          int kg = kt * 64 + nt * 16 + quad * 4;
#pragma unroll
          for (int r = 0; r < 4; ++r)
            if (kg + r > qg) sc[s][nt][r] = -1e30f;
        }
      }
    }

    // fixed-base softmax numerator + P^T B-frag transform.
    union { int i[4]; short8 v; } pf[2][2];
#pragma unroll
    for (int s = 0; s < 2; ++s) {
      int pk[4][2];
#pragma unroll
      for (int nt = 0; nt < 4; ++nt) {
        float p0 = __builtin_amdgcn_exp2f(sc[s][nt][0]);
        float p1 = __builtin_amdgcn_exp2f(sc[s][nt][1]);
        float p2 = __builtin_amdgcn_exp2f(sc[s][nt][2]);
        float p3 = __builtin_amdgcn_exp2f(sc[s][nt][3]);
        rsum[s] += (p0 + p1) + (p2 + p3);
        pk[nt][0] = pkbf(p0, p1);
        pk[nt][1] = pkbf(p2, p3);
      }
      // quad-redistribution in-register:
      //   permlane32_swap(A,C): A'=[a@q0,a@q1,c@q0,c@q1] C'=[a@q2,a@q3,c@q2,c@q3]
      //   permlane16_swap(A',C'): A''=[a@q0,a@q2,c@q0,c@q2]=i[0]
      //                           C''=[a@q1,a@q3,c@q1,c@q3]=i[2]
#pragma unroll
      for (int t = 0; t < 2; ++t) {
        int A = pk[t * 2][0], C = pk[t * 2 + 1][0];
        int B2 = pk[t * 2][1], D = pk[t * 2 + 1][1];
        asm("v_permlane32_swap_b32 %0, %1" : "+v"(A), "+v"(C));
        asm("v_permlane16_swap_b32 %0, %1" : "+v"(A), "+v"(C));
        asm("v_permlane32_swap_b32 %0, %1" : "+v"(B2), "+v"(D));
        asm("v_permlane16_swap_b32 %0, %1" : "+v"(B2), "+v"(D));
        pf[s][t].i[0] = A;
        pf[s][t].i[1] = B2;
        pf[s][t].i[2] = C;
        pf[s][t].i[3] = D;
      }
    }

    // O^T += V^T P^T (V A-frags shared across strips)
    __builtin_amdgcn_s_setprio(1);
#pragma unroll
    for (int ntd = 0; ntd < 4; ++ntd) {
      short8 v0 = *(const short8*)(Vb + (ntd * 16 + l16) * 64 + ((quad ^ l7) << 3));
      short8 v1 = *(const short8*)(Vb + (ntd * 16 + l16) * 64 + (((4 + quad) ^ l7) << 3));
#pragma unroll
      for (int s = 0; s < 2; ++s) {
        o[ntd][s] = __builtin_amdgcn_mfma_f32_16x16x32_bf16(v0, pf[s][0].v, o[ntd][s], 0, 0, 0);
        o[ntd][s] = __builtin_amdgcn_mfma_f32_16x16x32_bf16(v1, pf[s][1].v, o[ntd][s], 0, 0, 0);
      }
    }
    __builtin_amdgcn_s_setprio(0);
  }

  // l reduction over quads (linear softmax base -> once at the end)
#pragma unroll
  for (int s = 0; s < 2; ++s) {
    rsum[s] += __shfl_xor(rsum[s], 16, 64);
    rsum[s] += __shfl_xor(rsum[s], 32, 64);
  }

  // epilogue: O^T -> LDS transpose -> coalesced stores
  __syncthreads();
  unsigned short* Os = smem;  // [128 q][72]
#pragma unroll
  for (int s = 0; s < 2; ++s) {
    float invl = 1.0f / rsum[s];
#pragma unroll
    for (int ntd = 0; ntd < 4; ++ntd) {
      us4 pk4;
#pragma unroll
      for (int r = 0; r < 4; ++r) pk4[r] = f2bf(o[ntd][s][r] * invl);
      *(us4*)(Os + (wave * 32 + s * 16 + l16) * 72 + ntd * 16 + quad * 4) = pk4;
    }
  }
  __syncthreads();
  const int b = bh >> 4, h = bh & 15;
#pragma unroll
  for (int it = 0; it < 4; ++it) {
    int e = it * 256 + tid;
    int row = e >> 3, c = (e & 7) * 8;
    short8 vrow = *(const short8*)(Os + row * 72 + c);
    *(short8*)(ctx + (size_t)(b * S_LEN + q0 + row) * D_MODEL + h * HEAD_DIM + c) = vrow;
  }
}

// ---------- launch ----------
extern "C" void kernel_launch(void* const* d_in, const int* in_sizes, int n_in,
                              void* d_out, int out_size, void* d_ws, size_t ws_size,
                              hipStream_t stream) {
  (void)in_sizes; (void)n_in; (void)out_size;
  const float* q  = (const float*)d_in[0];
  const float* k  = (const float*)d_in[1];
  const float* v  = (const float*)d_in[2];
  const float* Wq = (const float*)d_in[4];
  const float* bq = (const float*)d_in[5];
  const float* Wk = (const float*)d_in[6];
  const float* bk = (const float*)d_in[7];
  const float* Wv = (const float*)d_in[8];
  const float* bv = (const float*)d_in[9];
  const float* Wo = (const float*)d_in[10];
  const float* bo = (const float*)d_in[11];
  float* out = (float*)d_out;

  if (ws_size < 109051904u) return;
  char* ws = (char*)d_ws;
  unsigned short* xq    = (unsigned short*)(ws);
  unsigned short* xk    = (unsigned short*)(ws + 16777216);
  unsigned short* xv    = (unsigned short*)(ws + 33554432);
  unsigned short* wqkvT = (unsigned short*)(ws + 50331648);  // [3072][1024] = 6 MB
  unsigned short* woT   = (unsigned short*)(ws + 56623104);
  unsigned short* qh    = (unsigned short*)(ws + 58720256);
  unsigned short* kh    = qh + 8388608;
  unsigned short* vt    = kh + 8388608;  // [B,H,64,S] written directly by proj<0>
  unsigned short* ctx   = xq;            // xq dead after QKV projection

  static int attr_done = 0;
  if (!attr_done) {
    auto* k0f = proj_gemm<0>;
    auto* k1f = proj_gemm<1>;
    hipFuncSetAttribute(reinterpret_cast<const void*>(k0f),
                        hipFuncAttributeMaxDynamicSharedMemorySize, 147456);
    hipFuncSetAttribute(reinterpret_cast<const void*>(k1f),
                        hipFuncAttributeMaxDynamicSharedMemorySize, 147456);
    attr_done = 1;
  }

  cvt3_kernel<<<12288, 256, 0, stream>>>(q, k, v, xq, xk, xv);
  transpose_w4<<<dim3(16, 16, 4), 256, 0, stream>>>(Wq, Wk, Wv, Wo, wqkvT, woT);
  // fused QKV projection; Q scale folds 1/sqrt(64) and log2(e)
  proj_gemm<0><<<dim3(24, 32), 512, 147456, stream>>>(xq, xk, xv, wqkvT, bq, bk, bv,
                                                      qh, kh, vt, 0.125f * 1.44269504088896f);
  flash_attn<<<dim3(16, 64), 256, 0, stream>>>(qh, kh, vt, ctx);
  proj_gemm<1><<<dim3(8, 32), 512, 147456, stream>>>(ctx, ctx, ctx, woT, bo, bo, bo,
                                                     out, out, out, 1.0f);
}